// Round 8
// baseline (380.735 us; speedup 1.0000x reference)
//
#include <hip/hip_runtime.h>

// Problem constants (fixed by the reference).
#define N_SPK 1024
#define M_UTT 32
#define D_EMB 512
#define NROWS (N_SPK * M_UTT)   // 32768

#define NEG_INF (-__builtin_inff())

using f16x8 = __attribute__((ext_vector_type(8))) _Float16;
using f32x4 = __attribute__((ext_vector_type(4))) float;

// ===========================================================================
// FAST PATH: single-pass f16 MFMA GEMM + exact fp32 diagonal.  ws ~39 MB.
//
// NOTE (round-6 lesson): the per-row softmax MUST carry a running max.
// The true loss (~0.00467) is dominated by ~one extreme row whose off-diag
// logits exceed its diag logit by ~150 nats; any representation that
// exponentiates relative to a fixed reference (e.g. dgl) overflows fp32.
// pm[row] = per-64-col (max, sumexp) partials is load-bearing.
// ===========================================================================

// Async global->LDS, 16 B per lane. Global addr is per-lane; LDS dest is
// wave-uniform base + lane*16.
__device__ __forceinline__ void gload16(const void* g, void* lds) {
    __builtin_amdgcn_global_load_lds(
        (const __attribute__((address_space(1))) void*)g,
        (__attribute__((address_space(3))) void*)lds, 16, 0, 0);
}

// ---------------------------------------------------------------------------
// prep: one block per speaker n (32 rows x 512 dims), 512 threads (8 waves).
// Wave w handles rows {mi*8 + w}, mi=0..3 -> 4 rows/thread serial depth.
//  - ehf[row] = (f16) e[row]                      (33.5 MB)
//  - ch[n]    = (f16) centroid                    (1 MB)
//  - dgl[row] = w*(e.sum + ||e||^2/31) + b  exact fp32 diag logit (131 KB)
//  - block 0 zeroes out[0] and cnt[256] (gemm's completion counters)
// ---------------------------------------------------------------------------
__global__ __launch_bounds__(512)
void prep_kernel(const float* __restrict__ e,
                 _Float16* __restrict__ ehf, _Float16* __restrict__ ch,
                 float* __restrict__ dgl, int* __restrict__ cnt,
                 const float* __restrict__ wp, const float* __restrict__ bp,
                 float* __restrict__ out) {
    __shared__ float csum[8][D_EMB];   // 16 KiB
    const int n = blockIdx.x;
    const int wv = threadIdx.x >> 6, l = threadIdx.x & 63;

    if (n == 0) {
        if (threadIdx.x == 0) out[0] = 0.f;
        if (threadIdx.x < 256) cnt[threadIdx.x] = 0;
    }

    float xs[4][8];     // retained row data (lane's 8 dims x 4 rows)
    float ssq[4];       // per-row ||e||^2 (wave-uniform after butterfly)
    float cacc[8];
#pragma unroll
    for (int j = 0; j < 8; ++j) cacc[j] = 0.f;

#pragma unroll
    for (int mi = 0; mi < 4; ++mi) {
        const int m = mi * 8 + wv;
        const size_t row = (size_t)n * M_UTT + m;
        const float* p = e + row * D_EMB + l * 8;
        float4 x0 = *(const float4*)p;
        float4 x1 = *(const float4*)(p + 4);
        xs[mi][0] = x0.x; xs[mi][1] = x0.y; xs[mi][2] = x0.z; xs[mi][3] = x0.w;
        xs[mi][4] = x1.x; xs[mi][5] = x1.y; xs[mi][6] = x1.z; xs[mi][7] = x1.w;
        f16x8 h;
        float sq = 0.f;
#pragma unroll
        for (int j = 0; j < 8; ++j) {
            float x = xs[mi][j];
            h[j] = (_Float16)x;
            cacc[j] += x;
            sq = __builtin_fmaf(x, x, sq);
        }
        *(f16x8*)(ehf + row * D_EMB + l * 8) = h;
#pragma unroll
        for (int off = 32; off; off >>= 1) sq += __shfl_xor(sq, off);
        ssq[mi] = sq;
    }

#pragma unroll
    for (int j = 0; j < 8; ++j) csum[wv][l * 8 + j] = cacc[j];
    __syncthreads();
    {
        const int d = threadIdx.x;   // 512 threads == D_EMB dims
        float s = 0.f;
#pragma unroll
        for (int wq = 0; wq < 8; ++wq) s += csum[wq][d];
        csum[0][d] = s;                               // full speaker sum
        ch[(size_t)n * D_EMB + d] = (_Float16)(s * (1.0f / M_UTT));
    }
    __syncthreads();

    // Exact fp32 diag: dgl[row] = w*(e.sum + ssq/31) + b.
    float sv[8];
#pragma unroll
    for (int j = 0; j < 8; ++j) sv[j] = csum[0][l * 8 + j];
    const float w = wp[0], bb = bp[0];
#pragma unroll
    for (int mi = 0; mi < 4; ++mi) {
        float dg = 0.f;
#pragma unroll
        for (int j = 0; j < 8; ++j) dg = __builtin_fmaf(xs[mi][j], sv[j], dg);
#pragma unroll
        for (int off = 32; off; off >>= 1) dg += __shfl_xor(dg, off);
        if (l == 0) {
            const size_t row = (size_t)n * M_UTT + mi * 8 + wv;
            dgl[row] = __builtin_fmaf(w, dg + ssq[mi] * (1.0f / 31.0f), bb);
        }
    }
}

// ---------------------------------------------------------------------------
// gemm_ls: 128x128 logit tile per block, single-pass f16 MFMA.  Per 64-half
// k-tile (8 tiles, fully unrolled): stage Ah (16 KB, waves 0/1) + Bh (16 KB,
// waves 2/3) via global_load_lds; 2 K-steps x 16 MFMA = 32 MFMA/barrier/wave.
// 32 KB LDS.
//
// LDS layout per buffer: 128 rows x 8 chunks(16B); phys chunk = c ^ (row&7)
// (permutation applied on the global source address, so global_load_lds's
// uniform-base + lane*16 dest holds; fragment ds_read_b128 is 2-way = free).
//
// Epilogue: logits, diag substitution from exact dgl[], per-64-col
// (max,sumexp) partials -> pm[row][ct*2+wx].  Then completion-counter fusion:
// the LAST of the 8 ct-blocks for this rt (device-scope atomic on cnt[rt],
// __threadfence release/acquire per G16) merges the panel's pm partials and
// atomicAdds the 128-row loss sum into out.
//
// XCD swizzle: blk&7 = XCD (round-robin dispatch); each XCD owns 32 rt,
// walking ct fastest -> A working set per XCD fits its L2.
// ---------------------------------------------------------------------------
__global__ __launch_bounds__(256, 4)
void gemm_ls_kernel(const _Float16* __restrict__ ehf,
                    const _Float16* __restrict__ ch,
                    const float* __restrict__ dgl,
                    const float* __restrict__ wp,
                    const float* __restrict__ bp,
                    float2* __restrict__ pm,
                    int* __restrict__ cnt,
                    float* __restrict__ out) {
    __shared__ _Float16 Ah[128 * 64];   // 16 KiB
    __shared__ _Float16 Bh[128 * 64];   // 16 KiB
    __shared__ int lastflag;
    __shared__ float redl[2];

    const int tid = threadIdx.x;
    const int wv = tid >> 6, l = tid & 63;
    const int wy = wv >> 1, wx = wv & 1;   // wave quadrant: rows wy*64+, cols wx*64+
    const int ln = l & 15, q = l >> 4;

    const int blk = blockIdx.x;
    const int ct = (blk >> 3) & 7;
    const int rt = (blk & 7) * 32 + (blk >> 6);
    const int r0 = rt * 128, c0 = ct * 128;

    f32x4 acc[4][4];
    f32x4 zz = {0.f, 0.f, 0.f, 0.f};
#pragma unroll
    for (int i = 0; i < 4; ++i)
#pragma unroll
        for (int j = 0; j < 4; ++j) acc[i][j] = zz;

    // Staging roles: waves 0,1 -> Ah halves; waves 2,3 -> Bh halves.
    const int half = wv & 1;                 // which 64-row half this wave fills
    const _Float16* src = (wv < 2)
        ? ehf + (size_t)(r0 + half * 64) * D_EMB
        : ch  + (size_t)(c0 + half * 64) * D_EMB;
    _Float16* dst = ((wv < 2) ? Ah : Bh) + half * 64 * 64;
    const int srl = l >> 3;                  // row within 8-row issue group
    const int sc  = l & 7;                   // physical chunk this lane fills

    // Per-lane fragment LDS offsets (halves), fixed across k-tiles.
    int offA[2][4], offB[2][4];
#pragma unroll
    for (int ks = 0; ks < 2; ++ks)
#pragma unroll
        for (int t = 0; t < 4; ++t) {
            int m = wy * 64 + t * 16 + ln;
            offA[ks][t] = m * 64 + (((ks * 4 + q) ^ (m & 7)) * 8);
            int mb = wx * 64 + t * 16 + ln;
            offB[ks][t] = mb * 64 + (((ks * 4 + q) ^ (mb & 7)) * 8);
        }

#pragma unroll
    for (int kt = 0; kt < 8; ++kt) {
        __syncthreads();   // previous tile's ds_reads done before overwrite
#pragma unroll
        for (int i = 0; i < 8; ++i) {
            int r = i * 8 + srl;                  // 0..63 local row
            int gch = sc ^ (r & 7);               // content k-chunk
            gload16(src + (size_t)r * D_EMB + kt * 64 + gch * 8,
                    dst + i * 512);
        }
        __syncthreads();   // barrier semantics drain vmcnt

#pragma unroll
        for (int ks = 0; ks < 2; ++ks) {
            f16x8 af[4], bf[4];
#pragma unroll
            for (int t = 0; t < 4; ++t) af[t] = *(const f16x8*)&Ah[offA[ks][t]];
#pragma unroll
            for (int t = 0; t < 4; ++t) bf[t] = *(const f16x8*)&Bh[offB[ks][t]];
#pragma unroll
            for (int i = 0; i < 4; ++i)
#pragma unroll
                for (int j = 0; j < 4; ++j)
                    acc[i][j] = __builtin_amdgcn_mfma_f32_16x16x32_f16(
                        af[i], bf[j], acc[i][j], 0, 0, 0);
        }
    }

    // ---- Epilogue: logits, exact-diag substitution, per-64-col (max,sumexp) --
    const float w = wp[0], bb = bp[0];
    const bool isDiag = (ct == (rt >> 5));

#pragma unroll
    for (int mt = 0; mt < 4; ++mt) {
#pragma unroll
        for (int r = 0; r < 4; ++r) {
            const int grow = r0 + wy * 64 + mt * 16 + q * 4 + r;
            const float dglv = isDiag ? dgl[grow] : 0.f;
            const int nloc = (grow >> 5) - c0;   // diag col, tile-local
            float lv[4];
#pragma unroll
            for (int nt = 0; nt < 4; ++nt) {
                float lg = __builtin_fmaf(w, acc[mt][nt][r], bb);
                if (isDiag && (wx * 64 + nt * 16 + ln) == nloc) lg = dglv;
                lv[nt] = lg;
            }
            float mx = fmaxf(fmaxf(lv[0], lv[1]), fmaxf(lv[2], lv[3]));
#pragma unroll
            for (int off = 8; off; off >>= 1) mx = fmaxf(mx, __shfl_xor(mx, off));
            float ss = 0.f;
#pragma unroll
            for (int nt = 0; nt < 4; ++nt) ss += __expf(lv[nt] - mx);
#pragma unroll
            for (int off = 8; off; off >>= 1) ss += __shfl_xor(ss, off);
            if (ln == 0) {
                float2 v2; v2.x = mx; v2.y = ss;
                pm[(size_t)grow * 16 + ct * 2 + wx] = v2;
            }
        }
    }

    // ---- Completion-counter fused rowloss (G16 release/acquire pattern) ----
    __syncthreads();         // all waves' pm stores issued
    __threadfence();         // publish this block's pm to device scope
    if (tid == 0) lastflag = (atomicAdd(&cnt[rt], 1) == 7);
    __syncthreads();
    if (lastflag) {
        __threadfence();     // acquire: other blocks' pm now visible
        float loss = 0.f;
        if (tid < 128) {
            const int row = r0 + tid;
            float M = NEG_INF, S = 0.f;
#pragma unroll
            for (int i = 0; i < 16; ++i) {
                float2 t = pm[(size_t)row * 16 + i];
                float nm = fmaxf(M, t.x);
                S = S * __expf(M - nm) + t.y * __expf(t.x - nm);
                M = nm;
            }
            loss = M + __logf(S) - dgl[row];
#pragma unroll
            for (int off = 32; off; off >>= 1) loss += __shfl_xor(loss, off);
            if ((tid & 63) == 0) redl[tid >> 6] = loss;
        }
        __syncthreads();
        if (tid == 0)
            atomicAdd(out, (redl[0] + redl[1]) * (1.0f / NROWS));
    }
}

// ===========================================================================
// FALLBACK PATH (round-1 fp32 vector kernels) — used if ws_size is too small.
// ===========================================================================

__global__ void centroid_kernel(const float* __restrict__ e,
                                float* __restrict__ cent) {
    int gid = blockIdx.x * 256 + threadIdx.x;
    int n = gid >> 9;
    int d = gid & 511;
    const float* p = e + ((size_t)n * M_UTT) * D_EMB + d;
    float s = 0.f;
#pragma unroll
    for (int m = 0; m < M_UTT; ++m) s += p[(size_t)m * D_EMB];
    cent[gid] = s * (1.0f / M_UTT);
}

__global__ void normsq_kernel(const float* __restrict__ e,
                              float* __restrict__ nsq) {
    int wv = threadIdx.x >> 6;
    int lane = threadIdx.x & 63;
    int row = blockIdx.x * 4 + wv;
    const float* p = e + (size_t)row * D_EMB + lane;
    float s = 0.f;
#pragma unroll
    for (int j = 0; j < 8; ++j) { float x = p[j * 64]; s += x * x; }
#pragma unroll
    for (int off = 32; off; off >>= 1) s += __shfl_xor(s, off);
    if (lane == 0) nsq[row] = s;
}

#define BR 64
#define BC 128
#define BK 16
#define TR 4
#define TC 8

__global__ __launch_bounds__(256, 2)
void ge2e_main(const float* __restrict__ e, const float* __restrict__ cent,
               const float* __restrict__ nsq, const float* __restrict__ wp,
               const float* __restrict__ bp, float* __restrict__ partials) {
    __shared__ float As[BK][BR];
    __shared__ float Bs[BK][BC];
    __shared__ float diagLs[BR];
    __shared__ float red[16];

    const int tid = threadIdx.x;
    const int tx = tid & 15;
    const int ty = tid >> 4;
    const int blk = blockIdx.x;
    const int r0 = blk * BR;

    const float w = *wp;
    const float bb = *bp;

    float m_run[TR], s_run[TR];
#pragma unroll
    for (int i = 0; i < TR; ++i) { m_run[i] = NEG_INF; s_run[i] = 0.f; }

    const int a_row = tid >> 2;
    const int a_k   = (tid & 3) * 4;
    const int b_col = tid >> 1;
    const int b_k   = (tid & 1) * 8;

    for (int ct = 0; ct < N_SPK / BC; ++ct) {
        const int c0 = ct * BC;
        float acc[TR][TC];
#pragma unroll
        for (int i = 0; i < TR; ++i)
#pragma unroll
            for (int j = 0; j < TC; ++j) acc[i][j] = 0.f;

        for (int kk = 0; kk < D_EMB; kk += BK) {
            __syncthreads();
            {
                float4 av = *(const float4*)(e + (size_t)(r0 + a_row) * D_EMB + kk + a_k);
                As[a_k + 0][a_row] = av.x;
                As[a_k + 1][a_row] = av.y;
                As[a_k + 2][a_row] = av.z;
                As[a_k + 3][a_row] = av.w;
            }
            {
                const float* bp0 = cent + (size_t)(c0 + b_col) * D_EMB + kk + b_k;
                float4 bv0 = *(const float4*)(bp0);
                float4 bv1 = *(const float4*)(bp0 + 4);
                Bs[b_k + 0][b_col] = bv0.x;
                Bs[b_k + 1][b_col] = bv0.y;
                Bs[b_k + 2][b_col] = bv0.z;
                Bs[b_k + 3][b_col] = bv0.w;
                Bs[b_k + 4][b_col] = bv1.x;
                Bs[b_k + 5][b_col] = bv1.y;
                Bs[b_k + 6][b_col] = bv1.z;
                Bs[b_k + 7][b_col] = bv1.w;
            }
            __syncthreads();

#pragma unroll
            for (int k = 0; k < BK; ++k) {
                float4 a4 = *(const float4*)&As[k][ty * TR];
                float4 b4a = *(const float4*)&Bs[k][tx * TC];
                float4 b4b = *(const float4*)&Bs[k][tx * TC + 4];
                float av[TR] = {a4.x, a4.y, a4.z, a4.w};
                float bv[TC] = {b4a.x, b4a.y, b4a.z, b4a.w,
                                b4b.x, b4b.y, b4b.z, b4b.w};
#pragma unroll
                for (int i = 0; i < TR; ++i)
#pragma unroll
                    for (int j = 0; j < TC; ++j)
                        acc[i][j] = __builtin_fmaf(av[i], bv[j], acc[i][j]);
            }
        }

#pragma unroll
        for (int i = 0; i < TR; ++i) {
            const int grow = r0 + ty * TR + i;
            const int dcol = grow >> 5;
            float lv[TC];
#pragma unroll
            for (int j = 0; j < TC; ++j) {
                const int gcol = c0 + tx * TC + j;
                float v = acc[i][j];
                float lg;
                if (gcol == dcol) {
                    lg = __builtin_fmaf(w, __builtin_fmaf(32.0f, v,
                             (1.0f / 31.0f) * nsq[grow]), bb);
                    diagLs[ty * TR + i] = lg;
                } else {
                    lg = __builtin_fmaf(w, v, bb);
                }
                lv[j] = lg;
            }
            float mx = lv[0];
#pragma unroll
            for (int j = 1; j < TC; ++j) mx = fmaxf(mx, lv[j]);
#pragma unroll
            for (int off = 8; off; off >>= 1) mx = fmaxf(mx, __shfl_xor(mx, off));
            float ss = 0.f;
#pragma unroll
            for (int j = 0; j < TC; ++j) ss += __expf(lv[j] - mx);
#pragma unroll
            for (int off = 8; off; off >>= 1) ss += __shfl_xor(ss, off);
            float nm = fmaxf(m_run[i], mx);
            s_run[i] = s_run[i] * __expf(m_run[i] - nm) + ss * __expf(mx - nm);
            m_run[i] = nm;
        }
    }

    __syncthreads();
    if (tx == 0) {
        float part = 0.f;
#pragma unroll
        for (int i = 0; i < TR; ++i) {
            const int lr = ty * TR + i;
            part += m_run[i] + __logf(s_run[i]) - diagLs[lr];
        }
        red[ty] = part;
    }
    __syncthreads();
    if (tid == 0) {
        float t = 0.f;
#pragma unroll
        for (int i = 0; i < 16; ++i) t += red[i];
        partials[blk] = t;
    }
}

__global__ void reduce_kernel(const float* __restrict__ partials,
                              float* __restrict__ out) {
    __shared__ float red[4];
    int tid = threadIdx.x;
    float v = partials[tid] + partials[tid + 256];
#pragma unroll
    for (int off = 32; off; off >>= 1) v += __shfl_xor(v, off);
    if ((tid & 63) == 0) red[tid >> 6] = v;
    __syncthreads();
    if (tid == 0)
        out[0] = (red[0] + red[1] + red[2] + red[3]) * (1.0f / NROWS);
}

// ===========================================================================

extern "C" void kernel_launch(void* const* d_in, const int* in_sizes, int n_in,
                              void* d_out, int out_size, void* d_ws, size_t ws_size,
                              hipStream_t stream) {
    const float* e  = (const float*)d_in[0];   // [1024,32,512] f32
    const float* wp = (const float*)d_in[1];   // scalar
    const float* bp = (const float*)d_in[2];   // scalar
    float* out = (float*)d_out;

    // Fast-path workspace layout (bytes, 256-aligned):
    //   ehf 33554432 | ch 1048576 | dgl 131072 | pm 4194304 | cnt 1024
    const size_t NEED_FAST = 33554432ull + 1048576ull + 131072ull
                           + 4194304ull + 1024ull;   // 38,929,408

    if (ws_size >= NEED_FAST) {
        char* base = (char*)d_ws;
        _Float16* ehf = (_Float16*)(base);
        _Float16* ch  = (_Float16*)(base + 33554432ull);
        float*    dgl = (float*)   (base + 34603008ull);
        float2*   pm  = (float2*)  (base + 34734080ull);
        int*      cnt = (int*)     (base + 38928384ull);

        prep_kernel<<<N_SPK, 512, 0, stream>>>(e, ehf, ch, dgl, cnt,
                                               wp, bp, out);
        gemm_ls_kernel<<<2048, 256, 0, stream>>>(ehf, ch, dgl, wp, bp,
                                                 pm, cnt, out);
    } else {
        float* ws = (float*)d_ws;
        float* cent     = ws;
        float* nsq      = ws + 524288;
        float* partials = ws + 524288 + 32768;

        centroid_kernel<<<N_SPK * D_EMB / 256, 256, 0, stream>>>(e, cent);
        normsq_kernel<<<NROWS / 4, 256, 0, stream>>>(e, nsq);
        ge2e_main<<<NROWS / BR, 256, 0, stream>>>(e, cent, nsq, wp, bp, partials);
        reduce_kernel<<<1, 256, 0, stream>>>(partials, out);
    }
}

// Round 9
// 171.060 us; speedup vs baseline: 2.2257x; 2.2257x over previous
//
#include <hip/hip_runtime.h>

// Problem constants (fixed by the reference).
#define N_SPK 1024
#define M_UTT 32
#define D_EMB 512
#define NROWS (N_SPK * M_UTT)   // 32768

#define NEG_INF (-__builtin_inff())

using f16x8 = __attribute__((ext_vector_type(8))) _Float16;
using f32x4 = __attribute__((ext_vector_type(4))) float;

// ===========================================================================
// FAST PATH: single-pass f16 MFMA GEMM + exact fp32 diagonal.  ws ~41 MB.
//
// Lessons encoded here:
//  - R6: per-row softmax MUST carry a running max (one extreme row has
//    off-diag logits ~150 nats above its diag; fixed-reference exp overflows).
//    pm[row] = per-64-col (max, sumexp) partials is load-bearing.
//  - R8: NO device-scope __threadfence() in wide kernels — on gfx950 it
//    implies L2 writeback/invalidate (XCD non-coherence) and serialized the
//    GEMM 5x.  Keep rowloss as a separate dispatch.
//  - R9: prep must be streaming-parallel (one wave per row), not
//    one-block-per-speaker with serial row loops.
// ===========================================================================

// Async global->LDS, 16 B per lane. Global addr is per-lane; LDS dest is
// wave-uniform base + lane*16.
__device__ __forceinline__ void gload16(const void* g, void* lds) {
    __builtin_amdgcn_global_load_lds(
        (const __attribute__((address_space(1))) void*)g,
        (__attribute__((address_space(3))) void*)lds, 16, 0, 0);
}

// ---------------------------------------------------------------------------
// centroid_f16: one thread per (n,d).  2048 blocks x 256.
//   sumf[n*512+d] = sum_m e[n][m][d]   (fp32, 2 MB — rowprep + nothing else)
//   ch[n*512+d]   = (f16)(sumf/32)
//   thread 0 zeroes out[0].
// ---------------------------------------------------------------------------
__global__ __launch_bounds__(256)
void centroid_f16_kernel(const float* __restrict__ e,
                         _Float16* __restrict__ ch,
                         float* __restrict__ sumf,
                         float* __restrict__ out) {
    const int gid = blockIdx.x * 256 + threadIdx.x;   // 0..524287
    if (gid == 0) out[0] = 0.f;
    const int n = gid >> 9;
    const int d = gid & 511;
    const float* p = e + ((size_t)n * M_UTT) * D_EMB + d;
    float s = 0.f;
#pragma unroll
    for (int m = 0; m < M_UTT; ++m) s += p[(size_t)m * D_EMB];
    sumf[gid] = s;
    ch[gid] = (_Float16)(s * (1.0f / M_UTT));
}

// ---------------------------------------------------------------------------
// rowprep: ONE WAVE PER ROW (8192 waves = single-shot 32 waves/CU).
// Lane l owns dims l*8..l*8+7.
//   ehf[row] = (f16) e[row]
//   dgl[row] = w*(e.sum + ||e||^2/31) + b   (exact fp32; sum from sumf)
// Two butterfly reductions per row, no serial loops.
// ---------------------------------------------------------------------------
__global__ __launch_bounds__(256)
void rowprep_kernel(const float* __restrict__ e,
                    const float* __restrict__ sumf,
                    _Float16* __restrict__ ehf,
                    float* __restrict__ dgl,
                    const float* __restrict__ wp,
                    const float* __restrict__ bp) {
    const int wv = threadIdx.x >> 6, l = threadIdx.x & 63;
    const int row = blockIdx.x * 4 + wv;
    const int n = row >> 5;

    const float* p = e + (size_t)row * D_EMB + l * 8;
    float4 x0 = *(const float4*)p;
    float4 x1 = *(const float4*)(p + 4);
    const float* sp = sumf + (size_t)n * D_EMB + l * 8;
    float4 s0 = *(const float4*)sp;
    float4 s1 = *(const float4*)(sp + 4);

    float xs[8] = {x0.x, x0.y, x0.z, x0.w, x1.x, x1.y, x1.z, x1.w};
    float sv[8] = {s0.x, s0.y, s0.z, s0.w, s1.x, s1.y, s1.z, s1.w};

    f16x8 h;
    float sq = 0.f, dg = 0.f;
#pragma unroll
    for (int j = 0; j < 8; ++j) {
        float x = xs[j];
        h[j] = (_Float16)x;
        sq = __builtin_fmaf(x, x, sq);
        dg = __builtin_fmaf(x, sv[j], dg);
    }
    *(f16x8*)(ehf + (size_t)row * D_EMB + l * 8) = h;

#pragma unroll
    for (int off = 32; off; off >>= 1) {
        sq += __shfl_xor(sq, off);
        dg += __shfl_xor(dg, off);
    }
    if (l == 0)
        dgl[row] = __builtin_fmaf(wp[0], dg + sq * (1.0f / 31.0f), bp[0]);
}

// ---------------------------------------------------------------------------
// gemm_ls: 128x128 logit tile per block, single-pass f16 MFMA.  Per 64-half
// k-tile (8 tiles): stage Ah (16 KB, waves 0/1) + Bh (16 KB, waves 2/3) via
// global_load_lds; 2 K-steps x 16 MFMA = 32 MFMA/barrier/wave.  32 KB LDS.
//
// LDS layout per buffer: 128 rows x 8 chunks(16B); phys chunk = c ^ (row&7)
// (permutation applied on the global source address, so global_load_lds's
// uniform-base + lane*16 dest holds; fragment ds_read_b128 is 2-way = free).
//
// Epilogue: logits, diag substitution from exact dgl[], per-64-col
// (max,sumexp) partials -> pm[row][ct*2+wx].
//
// XCD swizzle: blk&7 = XCD (round-robin dispatch); each XCD owns 32 rt,
// walking ct fastest -> A working set per XCD fits its L2.
// ---------------------------------------------------------------------------
__global__ __launch_bounds__(256, 4)
void gemm_ls_kernel(const _Float16* __restrict__ ehf,
                    const _Float16* __restrict__ ch,
                    const float* __restrict__ dgl,
                    const float* __restrict__ wp,
                    const float* __restrict__ bp,
                    float2* __restrict__ pm) {
    __shared__ _Float16 Ah[128 * 64];   // 16 KiB
    __shared__ _Float16 Bh[128 * 64];   // 16 KiB

    const int tid = threadIdx.x;
    const int wv = tid >> 6, l = tid & 63;
    const int wy = wv >> 1, wx = wv & 1;   // wave quadrant: rows wy*64+, cols wx*64+
    const int ln = l & 15, q = l >> 4;

    const int blk = blockIdx.x;
    const int ct = (blk >> 3) & 7;
    const int rt = (blk & 7) * 32 + (blk >> 6);
    const int r0 = rt * 128, c0 = ct * 128;

    f32x4 acc[4][4];
    f32x4 zz = {0.f, 0.f, 0.f, 0.f};
#pragma unroll
    for (int i = 0; i < 4; ++i)
#pragma unroll
        for (int j = 0; j < 4; ++j) acc[i][j] = zz;

    // Staging roles: waves 0,1 -> Ah halves; waves 2,3 -> Bh halves.
    const int half = wv & 1;                 // which 64-row half this wave fills
    const _Float16* src = (wv < 2)
        ? ehf + (size_t)(r0 + half * 64) * D_EMB
        : ch  + (size_t)(c0 + half * 64) * D_EMB;
    _Float16* dst = ((wv < 2) ? Ah : Bh) + half * 64 * 64;
    const int srl = l >> 3;                  // row within 8-row issue group
    const int sc  = l & 7;                   // physical chunk this lane fills

    // Per-lane fragment LDS offsets (halves), fixed across k-tiles.
    int offA[2][4], offB[2][4];
#pragma unroll
    for (int ks = 0; ks < 2; ++ks)
#pragma unroll
        for (int t = 0; t < 4; ++t) {
            int m = wy * 64 + t * 16 + ln;
            offA[ks][t] = m * 64 + (((ks * 4 + q) ^ (m & 7)) * 8);
            int mb = wx * 64 + t * 16 + ln;
            offB[ks][t] = mb * 64 + (((ks * 4 + q) ^ (mb & 7)) * 8);
        }

    for (int kt = 0; kt < 8; ++kt) {
        __syncthreads();   // previous tile's ds_reads done before overwrite
#pragma unroll
        for (int i = 0; i < 8; ++i) {
            int r = i * 8 + srl;                  // 0..63 local row
            int gch = sc ^ (r & 7);               // content k-chunk
            gload16(src + (size_t)r * D_EMB + kt * 64 + gch * 8,
                    dst + i * 512);
        }
        __syncthreads();   // barrier semantics drain vmcnt

#pragma unroll
        for (int ks = 0; ks < 2; ++ks) {
            f16x8 af[4], bf[4];
#pragma unroll
            for (int t = 0; t < 4; ++t) af[t] = *(const f16x8*)&Ah[offA[ks][t]];
#pragma unroll
            for (int t = 0; t < 4; ++t) bf[t] = *(const f16x8*)&Bh[offB[ks][t]];
#pragma unroll
            for (int i = 0; i < 4; ++i)
#pragma unroll
                for (int j = 0; j < 4; ++j)
                    acc[i][j] = __builtin_amdgcn_mfma_f32_16x16x32_f16(
                        af[i], bf[j], acc[i][j], 0, 0, 0);
        }
    }

    // ---- Epilogue: logits, exact-diag substitution, per-64-col (max,sumexp) --
    const float w = wp[0], bb = bp[0];
    const bool isDiag = (ct == (rt >> 5));

#pragma unroll
    for (int mt = 0; mt < 4; ++mt) {
#pragma unroll
        for (int r = 0; r < 4; ++r) {
            const int grow = r0 + wy * 64 + mt * 16 + q * 4 + r;
            const float dglv = isDiag ? dgl[grow] : 0.f;
            const int nloc = (grow >> 5) - c0;   // diag col, tile-local
            float lv[4];
#pragma unroll
            for (int nt = 0; nt < 4; ++nt) {
                float lg = __builtin_fmaf(w, acc[mt][nt][r], bb);
                if (isDiag && (wx * 64 + nt * 16 + ln) == nloc) lg = dglv;
                lv[nt] = lg;
            }
            float mx = fmaxf(fmaxf(lv[0], lv[1]), fmaxf(lv[2], lv[3]));
#pragma unroll
            for (int off = 8; off; off >>= 1) mx = fmaxf(mx, __shfl_xor(mx, off));
            float ss = 0.f;
#pragma unroll
            for (int nt = 0; nt < 4; ++nt) ss += __expf(lv[nt] - mx);
#pragma unroll
            for (int off = 8; off; off >>= 1) ss += __shfl_xor(ss, off);
            if (ln == 0) {
                float2 v2; v2.x = mx; v2.y = ss;
                pm[(size_t)grow * 16 + ct * 2 + wx] = v2;
            }
        }
    }
}

// ---------------------------------------------------------------------------
// rowloss: merge 16 (m,s) partials per row -> loss_row, block-reduce, then
// one device-scope atomicAdd into out (pre-zeroed by centroid_f16).
// ---------------------------------------------------------------------------
__global__ void rowloss_kernel(const float2* __restrict__ pm,
                               const float* __restrict__ dgl,
                               float* __restrict__ out) {
    __shared__ float red[4];
    const int tid = threadIdx.x;
    const int row = blockIdx.x * 256 + tid;
    float M = NEG_INF, S = 0.f;
#pragma unroll
    for (int i = 0; i < 16; ++i) {
        float2 t = pm[(size_t)row * 16 + i];
        float nm = fmaxf(M, t.x);
        S = S * __expf(M - nm) + t.y * __expf(t.x - nm);
        M = nm;
    }
    float loss = M + __logf(S) - dgl[row];
#pragma unroll
    for (int off = 32; off; off >>= 1) loss += __shfl_xor(loss, off);
    if ((tid & 63) == 0) red[tid >> 6] = loss;
    __syncthreads();
    if (tid == 0)
        atomicAdd(out, (red[0] + red[1] + red[2] + red[3]) * (1.0f / NROWS));
}

// ===========================================================================
// FALLBACK PATH (round-1 fp32 vector kernels) — used if ws_size is too small.
// ===========================================================================

__global__ void centroid_kernel(const float* __restrict__ e,
                                float* __restrict__ cent) {
    int gid = blockIdx.x * 256 + threadIdx.x;
    int n = gid >> 9;
    int d = gid & 511;
    const float* p = e + ((size_t)n * M_UTT) * D_EMB + d;
    float s = 0.f;
#pragma unroll
    for (int m = 0; m < M_UTT; ++m) s += p[(size_t)m * D_EMB];
    cent[gid] = s * (1.0f / M_UTT);
}

__global__ void normsq_kernel(const float* __restrict__ e,
                              float* __restrict__ nsq) {
    int wv = threadIdx.x >> 6;
    int lane = threadIdx.x & 63;
    int row = blockIdx.x * 4 + wv;
    const float* p = e + (size_t)row * D_EMB + lane;
    float s = 0.f;
#pragma unroll
    for (int j = 0; j < 8; ++j) { float x = p[j * 64]; s += x * x; }
#pragma unroll
    for (int off = 32; off; off >>= 1) s += __shfl_xor(s, off);
    if (lane == 0) nsq[row] = s;
}

#define BR 64
#define BC 128
#define BK 16
#define TR 4
#define TC 8

__global__ __launch_bounds__(256, 2)
void ge2e_main(const float* __restrict__ e, const float* __restrict__ cent,
               const float* __restrict__ nsq, const float* __restrict__ wp,
               const float* __restrict__ bp, float* __restrict__ partials) {
    __shared__ float As[BK][BR];
    __shared__ float Bs[BK][BC];
    __shared__ float diagLs[BR];
    __shared__ float red[16];

    const int tid = threadIdx.x;
    const int tx = tid & 15;
    const int ty = tid >> 4;
    const int blk = blockIdx.x;
    const int r0 = blk * BR;

    const float w = *wp;
    const float bb = *bp;

    float m_run[TR], s_run[TR];
#pragma unroll
    for (int i = 0; i < TR; ++i) { m_run[i] = NEG_INF; s_run[i] = 0.f; }

    const int a_row = tid >> 2;
    const int a_k   = (tid & 3) * 4;
    const int b_col = tid >> 1;
    const int b_k   = (tid & 1) * 8;

    for (int ct = 0; ct < N_SPK / BC; ++ct) {
        const int c0 = ct * BC;
        float acc[TR][TC];
#pragma unroll
        for (int i = 0; i < TR; ++i)
#pragma unroll
            for (int j = 0; j < TC; ++j) acc[i][j] = 0.f;

        for (int kk = 0; kk < D_EMB; kk += BK) {
            __syncthreads();
            {
                float4 av = *(const float4*)(e + (size_t)(r0 + a_row) * D_EMB + kk + a_k);
                As[a_k + 0][a_row] = av.x;
                As[a_k + 1][a_row] = av.y;
                As[a_k + 2][a_row] = av.z;
                As[a_k + 3][a_row] = av.w;
            }
            {
                const float* bp0 = cent + (size_t)(c0 + b_col) * D_EMB + kk + b_k;
                float4 bv0 = *(const float4*)(bp0);
                float4 bv1 = *(const float4*)(bp0 + 4);
                Bs[b_k + 0][b_col] = bv0.x;
                Bs[b_k + 1][b_col] = bv0.y;
                Bs[b_k + 2][b_col] = bv0.z;
                Bs[b_k + 3][b_col] = bv0.w;
                Bs[b_k + 4][b_col] = bv1.x;
                Bs[b_k + 5][b_col] = bv1.y;
                Bs[b_k + 6][b_col] = bv1.z;
                Bs[b_k + 7][b_col] = bv1.w;
            }
            __syncthreads();

#pragma unroll
            for (int k = 0; k < BK; ++k) {
                float4 a4 = *(const float4*)&As[k][ty * TR];
                float4 b4a = *(const float4*)&Bs[k][tx * TC];
                float4 b4b = *(const float4*)&Bs[k][tx * TC + 4];
                float av[TR] = {a4.x, a4.y, a4.z, a4.w};
                float bv[TC] = {b4a.x, b4a.y, b4a.z, b4a.w,
                                b4b.x, b4b.y, b4b.z, b4b.w};
#pragma unroll
                for (int i = 0; i < TR; ++i)
#pragma unroll
                    for (int j = 0; j < TC; ++j)
                        acc[i][j] = __builtin_fmaf(av[i], bv[j], acc[i][j]);
            }
        }

#pragma unroll
        for (int i = 0; i < TR; ++i) {
            const int grow = r0 + ty * TR + i;
            const int dcol = grow >> 5;
            float lv[TC];
#pragma unroll
            for (int j = 0; j < TC; ++j) {
                const int gcol = c0 + tx * TC + j;
                float v = acc[i][j];
                float lg;
                if (gcol == dcol) {
                    lg = __builtin_fmaf(w, __builtin_fmaf(32.0f, v,
                             (1.0f / 31.0f) * nsq[grow]), bb);
                    diagLs[ty * TR + i] = lg;
                } else {
                    lg = __builtin_fmaf(w, v, bb);
                }
                lv[j] = lg;
            }
            float mx = lv[0];
#pragma unroll
            for (int j = 1; j < TC; ++j) mx = fmaxf(mx, lv[j]);
#pragma unroll
            for (int off = 8; off; off >>= 1) mx = fmaxf(mx, __shfl_xor(mx, off));
            float ss = 0.f;
#pragma unroll
            for (int j = 0; j < TC; ++j) ss += __expf(lv[j] - mx);
#pragma unroll
            for (int off = 8; off; off >>= 1) ss += __shfl_xor(ss, off);
            float nm = fmaxf(m_run[i], mx);
            s_run[i] = s_run[i] * __expf(m_run[i] - nm) + ss * __expf(mx - nm);
            m_run[i] = nm;
        }
    }

    __syncthreads();
    if (tx == 0) {
        float part = 0.f;
#pragma unroll
        for (int i = 0; i < TR; ++i) {
            const int lr = ty * TR + i;
            part += m_run[i] + __logf(s_run[i]) - diagLs[lr];
        }
        red[ty] = part;
    }
    __syncthreads();
    if (tid == 0) {
        float t = 0.f;
#pragma unroll
        for (int i = 0; i < 16; ++i) t += red[i];
        partials[blk] = t;
    }
}

__global__ void reduce_kernel(const float* __restrict__ partials,
                              float* __restrict__ out) {
    __shared__ float red[4];
    int tid = threadIdx.x;
    float v = partials[tid] + partials[tid + 256];
#pragma unroll
    for (int off = 32; off; off >>= 1) v += __shfl_xor(v, off);
    if ((tid & 63) == 0) red[tid >> 6] = v;
    __syncthreads();
    if (tid == 0)
        out[0] = (red[0] + red[1] + red[2] + red[3]) * (1.0f / NROWS);
}

// ===========================================================================

extern "C" void kernel_launch(void* const* d_in, const int* in_sizes, int n_in,
                              void* d_out, int out_size, void* d_ws, size_t ws_size,
                              hipStream_t stream) {
    const float* e  = (const float*)d_in[0];   // [1024,32,512] f32
    const float* wp = (const float*)d_in[1];   // scalar
    const float* bp = (const float*)d_in[2];   // scalar
    float* out = (float*)d_out;

    // Fast-path workspace layout (bytes, 256-aligned):
    //   ehf 33554432 | ch 1048576 | dgl 131072 | pm 4194304 | sumf 2097152
    const size_t NEED_FAST = 33554432ull + 1048576ull + 131072ull
                           + 4194304ull + 2097152ull;   // 41,025,536

    if (ws_size >= NEED_FAST) {
        char* base = (char*)d_ws;
        _Float16* ehf  = (_Float16*)(base);
        _Float16* ch   = (_Float16*)(base + 33554432ull);
        float*    dgl  = (float*)   (base + 34603008ull);
        float2*   pm   = (float2*)  (base + 34734080ull);
        float*    sumf = (float*)   (base + 38928384ull);

        centroid_f16_kernel<<<N_SPK * D_EMB / 256, 256, 0, stream>>>(
            e, ch, sumf, out);
        rowprep_kernel<<<NROWS / 4, 256, 0, stream>>>(
            e, sumf, ehf, dgl, wp, bp);
        gemm_ls_kernel<<<2048, 256, 0, stream>>>(ehf, ch, dgl, wp, bp, pm);
        rowloss_kernel<<<NROWS / 256, 256, 0, stream>>>(pm, dgl, out);
    } else {
        float* ws = (float*)d_ws;
        float* cent     = ws;
        float* nsq      = ws + 524288;
        float* partials = ws + 524288 + 32768;

        centroid_kernel<<<N_SPK * D_EMB / 256, 256, 0, stream>>>(e, cent);
        normsq_kernel<<<NROWS / 4, 256, 0, stream>>>(e, nsq);
        ge2e_main<<<NROWS / BR, 256, 0, stream>>>(e, cent, nsq, wp, bp, partials);
        reduce_kernel<<<1, 256, 0, stream>>>(partials, out);
    }
}

// Round 10
// 131.046 us; speedup vs baseline: 2.9054x; 1.3053x over previous
//
#include <hip/hip_runtime.h>

// Problem constants (fixed by the reference).
#define N_SPK 1024
#define M_UTT 32
#define D_EMB 512
#define NROWS (N_SPK * M_UTT)   // 32768

#define NEG_INF (-__builtin_inff())
#define MARGIN 25.0f   // skip row iff dgl - rowbound >= MARGIN (err < 1.4e-8/row)

using f32x4 = __attribute__((ext_vector_type(4))) float;

// ===========================================================================
// FAST PATH (round 10): prune-then-compute.  The GEMM is gone.
//
// Math: dgl ≈ 2641 ± 630 while every off-diag logit is bounded by
// |w|·||e||·max||c|| + b ≈ 459 (Cauchy-Schwarz).  For rows with
// dgl - bound >= 25 nats, every exp(l - dgl) underflows to EXACTLY 0 in the
// reference too -> loss_row == 0 bit-exactly -> skip.  Expected survivors:
// ~10 rows of 32768 (the loss 0.00467 is ~one extreme row at z≈-4.4, per
// the R6 overflow incident).  Survivors get an exact fp32 1024-logit
// max-carrying logsumexp (R6 lesson: the running max is load-bearing).
//
// R8 lesson kept: no device-scope __threadfence in wide kernels; all
// cross-kernel deps go through dispatch boundaries (same stream).
// ===========================================================================

// ---------------------------------------------------------------------------
// init: zero the accumulators that later kernels atomically update.
// (Separate dispatch: d_ws is poisoned 0xAA before every call, and folding
// the zeroing into prep would race with other blocks' atomics.)
// ---------------------------------------------------------------------------
__global__ void init_kernel(float* __restrict__ out, int* __restrict__ count,
                            int* __restrict__ cmax_i) {
    if (threadIdx.x == 0) { out[0] = 0.f; *count = 0; *cmax_i = 0; }
}

// ---------------------------------------------------------------------------
// prep: one block per speaker n (32 rows x 512 dims).  Reads e ONCE.
//  - sumf[n*512+d] = sum_m e[n][m][d]      (fp32 speaker sum, 2 MB)
//  - ssqA[row]     = ||e_row||^2
//  - dgl[row]      = w*(e.sum + ||e||^2/31) + b   (exact fp32 diag logit)
//  - atomicMax(cmax_i, ||c_n||^2)          (positive floats: int-monotone)
// Row data retained in registers across the centroid barrier (R7-verified).
// ---------------------------------------------------------------------------
__global__ __launch_bounds__(256)
void prep_kernel(const float* __restrict__ e,
                 float* __restrict__ sumf, float* __restrict__ ssqA,
                 float* __restrict__ dgl, int* __restrict__ cmax_i,
                 const float* __restrict__ wp, const float* __restrict__ bp) {
    __shared__ float csum[4][D_EMB];   // 8 KiB
    __shared__ float c2red[4];
    const int n = blockIdx.x;
    const int wv = threadIdx.x >> 6, l = threadIdx.x & 63;

    float xs[8][8];     // retained row data (lane's 8 dims x 8 rows)
    float ssq[8];       // per-row ||e||^2 (wave-uniform after butterfly)
    float cacc[8];
#pragma unroll
    for (int j = 0; j < 8; ++j) cacc[j] = 0.f;

#pragma unroll
    for (int mi = 0; mi < 8; ++mi) {
        const int m = mi * 4 + wv;
        const size_t row = (size_t)n * M_UTT + m;
        const float* p = e + row * D_EMB + l * 8;
        float4 x0 = *(const float4*)p;
        float4 x1 = *(const float4*)(p + 4);
        xs[mi][0] = x0.x; xs[mi][1] = x0.y; xs[mi][2] = x0.z; xs[mi][3] = x0.w;
        xs[mi][4] = x1.x; xs[mi][5] = x1.y; xs[mi][6] = x1.z; xs[mi][7] = x1.w;
        float sq = 0.f;
#pragma unroll
        for (int j = 0; j < 8; ++j) {
            float x = xs[mi][j];
            cacc[j] += x;
            sq = __builtin_fmaf(x, x, sq);
        }
#pragma unroll
        for (int off = 32; off; off >>= 1) sq += __shfl_xor(sq, off);
        ssq[mi] = sq;
        if (l == 0) ssqA[row] = sq;
    }

#pragma unroll
    for (int j = 0; j < 8; ++j) csum[wv][l * 8 + j] = cacc[j];
    __syncthreads();
    float c2acc = 0.f;
    for (int d = threadIdx.x; d < D_EMB; d += 256) {
        float s = csum[0][d] + csum[1][d] + csum[2][d] + csum[3][d];
        csum[0][d] = s;                               // full speaker sum
        sumf[(size_t)n * D_EMB + d] = s;
        float c = s * (1.0f / M_UTT);
        c2acc = __builtin_fmaf(c, c, c2acc);
    }
#pragma unroll
    for (int off = 32; off; off >>= 1) c2acc += __shfl_xor(c2acc, off);
    if (l == 0) c2red[wv] = c2acc;
    __syncthreads();   // csum[0] full sums + c2red visible
    if (threadIdx.x == 0) {
        float c2 = c2red[0] + c2red[1] + c2red[2] + c2red[3];
        atomicMax(cmax_i, __float_as_int(c2));   // c2 > 0: int order == float
    }

    // Exact fp32 diag: dgl[row] = w*(e.sum + ssq/31) + b.
    float sv[8];
#pragma unroll
    for (int j = 0; j < 8; ++j) sv[j] = csum[0][l * 8 + j];
    const float w = wp[0], bb = bp[0];
#pragma unroll
    for (int mi = 0; mi < 8; ++mi) {
        float dg = 0.f;
#pragma unroll
        for (int j = 0; j < 8; ++j) dg = __builtin_fmaf(xs[mi][j], sv[j], dg);
#pragma unroll
        for (int off = 32; off; off >>= 1) dg += __shfl_xor(dg, off);
        if (l == 0) {
            const size_t row = (size_t)n * M_UTT + mi * 4 + wv;
            dgl[row] = __builtin_fmaf(w, dg + ssq[mi] * (1.0f / 31.0f), bb);
        }
    }
}

// ---------------------------------------------------------------------------
// select: one thread per row.  Row survives iff dgl - (|w|*||e||*Cmax + b)
// < MARGIN.  Survivors appended to active[] (device atomic; ~10 appends).
// ---------------------------------------------------------------------------
__global__ __launch_bounds__(256)
void select_kernel(const float* __restrict__ ssqA, const float* __restrict__ dgl,
                   const int* __restrict__ cmax_i,
                   const float* __restrict__ wp, const float* __restrict__ bp,
                   int* __restrict__ count, int* __restrict__ active) {
    const int row = blockIdx.x * 256 + threadIdx.x;
    const float Cmax = __builtin_sqrtf(__int_as_float(*cmax_i));
    const float bound = __builtin_fmaf(
        __builtin_fabsf(wp[0]) * __builtin_sqrtf(ssqA[row]), Cmax, bp[0]);
    if (dgl[row] - bound < MARGIN) {
        int slot = atomicAdd(count, 1);
        active[slot] = row;
    }
}

// ---------------------------------------------------------------------------
// active: exact fp32 logsumexp for surviving rows.  Work item = (slot, chunk
// of 256 speakers); grid-stride (graph-safe for any count; expected ~40
// items).  e_row cached in LDS (broadcast reads); sumf rows streamed via L1.
// Emits per-chunk (max, sumexp) partials -> pmA[slot*4+chunk].
// ---------------------------------------------------------------------------
__global__ __launch_bounds__(256)
void active_kernel(const float* __restrict__ e, const float* __restrict__ sumf,
                   const float* __restrict__ dgl,
                   const int* __restrict__ count, const int* __restrict__ active,
                   const float* __restrict__ wp, const float* __restrict__ bp,
                   float2* __restrict__ pmA) {
    __shared__ float er[D_EMB];
    __shared__ float2 red2[4];
    const int tid = threadIdx.x;
    const int items = (*count) * 4;
    const float w = wp[0], bb = bp[0];

    for (int item = blockIdx.x; item < items; item += gridDim.x) {
        const int slot = item >> 2, chunk = item & 3;
        const int row = active[slot];
        __syncthreads();   // protect er/red2 from previous iteration
        er[tid] = e[(size_t)row * D_EMB + tid];
        er[tid + 256] = e[(size_t)row * D_EMB + 256 + tid];
        __syncthreads();

        const int j = chunk * 256 + tid;          // speaker (column) index
        const float* sp = sumf + (size_t)j * D_EMB;
        float d0 = 0.f, d1 = 0.f, d2 = 0.f, d3 = 0.f;
        for (int k = 0; k < D_EMB; k += 4) {
            float4 s4 = *(const float4*)(sp + k);
            d0 = __builtin_fmaf(er[k + 0], s4.x, d0);
            d1 = __builtin_fmaf(er[k + 1], s4.y, d1);
            d2 = __builtin_fmaf(er[k + 2], s4.z, d2);
            d3 = __builtin_fmaf(er[k + 3], s4.w, d3);
        }
        const float dot = (d0 + d1) + (d2 + d3);
        float lg = __builtin_fmaf(w, dot * (1.0f / M_UTT), bb);
        if (j == (row >> 5)) lg = dgl[row];       // exact diag substitution

        float mx = lg;
#pragma unroll
        for (int off = 32; off; off >>= 1) mx = fmaxf(mx, __shfl_xor(mx, off));
        float ss = __expf(lg - mx);
#pragma unroll
        for (int off = 32; off; off >>= 1) ss += __shfl_xor(ss, off);
        if ((tid & 63) == 0) { float2 v; v.x = mx; v.y = ss; red2[tid >> 6] = v; }
        __syncthreads();
        if (tid == 0) {
            float M = fmaxf(fmaxf(red2[0].x, red2[1].x),
                            fmaxf(red2[2].x, red2[3].x));
            float S = red2[0].y * __expf(red2[0].x - M)
                    + red2[1].y * __expf(red2[1].x - M)
                    + red2[2].y * __expf(red2[2].x - M)
                    + red2[3].y * __expf(red2[3].x - M);
            float2 v; v.x = M; v.y = S;
            pmA[slot * 4 + chunk] = v;
        }
    }
}

// ---------------------------------------------------------------------------
// merge: per active slot, combine 4 (max,sumexp) partials -> row loss,
// atomicAdd into out.  Skipped rows contribute exactly 0 (as in the ref).
// ---------------------------------------------------------------------------
__global__ __launch_bounds__(256)
void merge_kernel(const float2* __restrict__ pmA, const int* __restrict__ count,
                  const int* __restrict__ active, const float* __restrict__ dgl,
                  float* __restrict__ out) {
    const int cnt = *count;
    for (int slot = blockIdx.x * 256 + threadIdx.x; slot < cnt;
         slot += gridDim.x * 256) {
        float2 p0 = pmA[slot * 4 + 0];
        float2 p1 = pmA[slot * 4 + 1];
        float2 p2 = pmA[slot * 4 + 2];
        float2 p3 = pmA[slot * 4 + 3];
        float M = fmaxf(fmaxf(p0.x, p1.x), fmaxf(p2.x, p3.x));
        float S = p0.y * __expf(p0.x - M) + p1.y * __expf(p1.x - M)
                + p2.y * __expf(p2.x - M) + p3.y * __expf(p3.x - M);
        float loss = M + __logf(S) - dgl[active[slot]];
        atomicAdd(out, loss * (1.0f / NROWS));
    }
}

// ===========================================================================
// FALLBACK PATH (round-1 fp32 vector kernels) — used if ws_size is too small.
// ===========================================================================

__global__ void centroid_kernel(const float* __restrict__ e,
                                float* __restrict__ cent) {
    int gid = blockIdx.x * 256 + threadIdx.x;
    int n = gid >> 9;
    int d = gid & 511;
    const float* p = e + ((size_t)n * M_UTT) * D_EMB + d;
    float s = 0.f;
#pragma unroll
    for (int m = 0; m < M_UTT; ++m) s += p[(size_t)m * D_EMB];
    cent[gid] = s * (1.0f / M_UTT);
}

__global__ void normsq_kernel(const float* __restrict__ e,
                              float* __restrict__ nsq) {
    int wv = threadIdx.x >> 6;
    int lane = threadIdx.x & 63;
    int row = blockIdx.x * 4 + wv;
    const float* p = e + (size_t)row * D_EMB + lane;
    float s = 0.f;
#pragma unroll
    for (int j = 0; j < 8; ++j) { float x = p[j * 64]; s += x * x; }
#pragma unroll
    for (int off = 32; off; off >>= 1) s += __shfl_xor(s, off);
    if (lane == 0) nsq[row] = s;
}

#define BR 64
#define BC 128
#define BK 16
#define TR 4
#define TC 8

__global__ __launch_bounds__(256, 2)
void ge2e_main(const float* __restrict__ e, const float* __restrict__ cent,
               const float* __restrict__ nsq, const float* __restrict__ wp,
               const float* __restrict__ bp, float* __restrict__ partials) {
    __shared__ float As[BK][BR];
    __shared__ float Bs[BK][BC];
    __shared__ float diagLs[BR];
    __shared__ float red[16];

    const int tid = threadIdx.x;
    const int tx = tid & 15;
    const int ty = tid >> 4;
    const int blk = blockIdx.x;
    const int r0 = blk * BR;

    const float w = *wp;
    const float bb = *bp;

    float m_run[TR], s_run[TR];
#pragma unroll
    for (int i = 0; i < TR; ++i) { m_run[i] = NEG_INF; s_run[i] = 0.f; }

    const int a_row = tid >> 2;
    const int a_k   = (tid & 3) * 4;
    const int b_col = tid >> 1;
    const int b_k   = (tid & 1) * 8;

    for (int ct = 0; ct < N_SPK / BC; ++ct) {
        const int c0 = ct * BC;
        float acc[TR][TC];
#pragma unroll
        for (int i = 0; i < TR; ++i)
#pragma unroll
            for (int j = 0; j < TC; ++j) acc[i][j] = 0.f;

        for (int kk = 0; kk < D_EMB; kk += BK) {
            __syncthreads();
            {
                float4 av = *(const float4*)(e + (size_t)(r0 + a_row) * D_EMB + kk + a_k);
                As[a_k + 0][a_row] = av.x;
                As[a_k + 1][a_row] = av.y;
                As[a_k + 2][a_row] = av.z;
                As[a_k + 3][a_row] = av.w;
            }
            {
                const float* bp0 = cent + (size_t)(c0 + b_col) * D_EMB + kk + b_k;
                float4 bv0 = *(const float4*)(bp0);
                float4 bv1 = *(const float4*)(bp0 + 4);
                Bs[b_k + 0][b_col] = bv0.x;
                Bs[b_k + 1][b_col] = bv0.y;
                Bs[b_k + 2][b_col] = bv0.z;
                Bs[b_k + 3][b_col] = bv0.w;
                Bs[b_k + 4][b_col] = bv1.x;
                Bs[b_k + 5][b_col] = bv1.y;
                Bs[b_k + 6][b_col] = bv1.z;
                Bs[b_k + 7][b_col] = bv1.w;
            }
            __syncthreads();

#pragma unroll
            for (int k = 0; k < BK; ++k) {
                float4 a4 = *(const float4*)&As[k][ty * TR];
                float4 b4a = *(const float4*)&Bs[k][tx * TC];
                float4 b4b = *(const float4*)&Bs[k][tx * TC + 4];
                float av[TR] = {a4.x, a4.y, a4.z, a4.w};
                float bv[TC] = {b4a.x, b4a.y, b4a.z, b4a.w,
                                b4b.x, b4b.y, b4b.z, b4b.w};
#pragma unroll
                for (int i = 0; i < TR; ++i)
#pragma unroll
                    for (int j = 0; j < TC; ++j)
                        acc[i][j] = __builtin_fmaf(av[i], bv[j], acc[i][j]);
            }
        }

#pragma unroll
        for (int i = 0; i < TR; ++i) {
            const int grow = r0 + ty * TR + i;
            const int dcol = grow >> 5;
            float lv[TC];
#pragma unroll
            for (int j = 0; j < TC; ++j) {
                const int gcol = c0 + tx * TC + j;
                float v = acc[i][j];
                float lg;
                if (gcol == dcol) {
                    lg = __builtin_fmaf(w, __builtin_fmaf(32.0f, v,
                             (1.0f / 31.0f) * nsq[grow]), bb);
                    diagLs[ty * TR + i] = lg;
                } else {
                    lg = __builtin_fmaf(w, v, bb);
                }
                lv[j] = lg;
            }
            float mx = lv[0];
#pragma unroll
            for (int j = 1; j < TC; ++j) mx = fmaxf(mx, lv[j]);
#pragma unroll
            for (int off = 8; off; off >>= 1) mx = fmaxf(mx, __shfl_xor(mx, off));
            float ss = 0.f;
#pragma unroll
            for (int j = 0; j < TC; ++j) ss += __expf(lv[j] - mx);
#pragma unroll
            for (int off = 8; off; off >>= 1) ss += __shfl_xor(ss, off);
            float nm = fmaxf(m_run[i], mx);
            s_run[i] = s_run[i] * __expf(m_run[i] - nm) + ss * __expf(mx - nm);
            m_run[i] = nm;
        }
    }

    __syncthreads();
    if (tx == 0) {
        float part = 0.f;
#pragma unroll
        for (int i = 0; i < TR; ++i) {
            const int lr = ty * TR + i;
            part += m_run[i] + __logf(s_run[i]) - diagLs[lr];
        }
        red[ty] = part;
    }
    __syncthreads();
    if (tid == 0) {
        float t = 0.f;
#pragma unroll
        for (int i = 0; i < 16; ++i) t += red[i];
        partials[blk] = t;
    }
}

__global__ void reduce_kernel(const float* __restrict__ partials,
                              float* __restrict__ out) {
    __shared__ float red[4];
    int tid = threadIdx.x;
    float v = partials[tid] + partials[tid + 256];
#pragma unroll
    for (int off = 32; off; off >>= 1) v += __shfl_xor(v, off);
    if ((tid & 63) == 0) red[tid >> 6] = v;
    __syncthreads();
    if (tid == 0)
        out[0] = (red[0] + red[1] + red[2] + red[3]) * (1.0f / NROWS);
}

// ===========================================================================

extern "C" void kernel_launch(void* const* d_in, const int* in_sizes, int n_in,
                              void* d_out, int out_size, void* d_ws, size_t ws_size,
                              hipStream_t stream) {
    const float* e  = (const float*)d_in[0];   // [1024,32,512] f32
    const float* wp = (const float*)d_in[1];   // scalar
    const float* bp = (const float*)d_in[2];   // scalar
    float* out = (float*)d_out;

    // Fast-path workspace layout (bytes):
    //   sumf 2097152 | ssqA 131072 | dgl 131072 | active 131072 |
    //   pmA 1048576 | count 4 | cmax 4  (pad to 3,539,200)
    const size_t NEED_FAST = 3539200ull;

    if (ws_size >= NEED_FAST) {
        char* base = (char*)d_ws;
        float* sumf   = (float*)(base);
        float* ssqA   = (float*)(base + 2097152ull);
        float* dgl    = (float*)(base + 2228224ull);
        int*   active = (int*)  (base + 2359296ull);
        float2* pmA   = (float2*)(base + 2490368ull);
        int*   count  = (int*)  (base + 3538944ull);
        int*   cmax_i = (int*)  (base + 3538948ull);

        init_kernel<<<1, 64, 0, stream>>>(out, count, cmax_i);
        prep_kernel<<<N_SPK, 256, 0, stream>>>(e, sumf, ssqA, dgl, cmax_i,
                                               wp, bp);
        select_kernel<<<NROWS / 256, 256, 0, stream>>>(ssqA, dgl, cmax_i,
                                                       wp, bp, count, active);
        active_kernel<<<512, 256, 0, stream>>>(e, sumf, dgl, count, active,
                                               wp, bp, pmA);
        merge_kernel<<<8, 256, 0, stream>>>(pmA, count, active, dgl, out);
    } else {
        float* ws = (float*)d_ws;
        float* cent     = ws;
        float* nsq      = ws + 524288;
        float* partials = ws + 524288 + 32768;

        centroid_kernel<<<N_SPK * D_EMB / 256, 256, 0, stream>>>(e, cent);
        normsq_kernel<<<NROWS / 4, 256, 0, stream>>>(e, nsq);
        ge2e_main<<<NROWS / BR, 256, 0, stream>>>(e, cent, nsq, wp, bp, partials);
        reduce_kernel<<<1, 256, 0, stream>>>(partials, out);
    }
}